// Round 11
// baseline (149.917 us; speedup 1.0000x reference)
//
#include <hip/hip_runtime.h>
#include <stdint.h>

#define NB 4
#define NT 2048
#define ND 512
#define NH 8
#define NDK 64
#define NM (NB*NT)   // 8192 rows

typedef __attribute__((ext_vector_type(8))) short short8;
typedef __attribute__((ext_vector_type(4))) float f32x4;

// round-to-nearest-even fp32 -> bf16
__device__ __forceinline__ unsigned short f2b(float f) {
    union { float f; uint32_t u; } v; v.f = f;
    return (unsigned short)((v.u + 0x7FFFu + ((v.u >> 16) & 1u)) >> 16);
}

__device__ __forceinline__ void load_lds16(const void* g, void* l) {
    void* gn = const_cast<void*>(g);
    __builtin_amdgcn_global_load_lds((__attribute__((address_space(1))) void*)gn,
                                     (__attribute__((address_space(3))) void*)l,
                                     16, 0, 0);
}

// ---------------------------------------------------------------------------
// fp32 -> bf16 conversion of x + Wq,Wk,Wv,Wo, packed into ws.
// ---------------------------------------------------------------------------
__global__ void convert_all(const float* __restrict__ x,  const float* __restrict__ wq,
                            const float* __restrict__ wk, const float* __restrict__ wv,
                            const float* __restrict__ wo, unsigned short* __restrict__ dst) {
    size_t i = ((size_t)blockIdx.x * 256 + threadIdx.x) * 4;
    const float* src; size_t off;
    if (i < 4194304) { src = x; off = i; }
    else {
        size_t j = i - 4194304;
        src = (j < 262144) ? wq : (j < 524288) ? wk : (j < 786432) ? wv : wo;
        off = j & 262143;
    }
    f32x4 v = *(const f32x4*)(src + off);
    ushort4 r;
    r.x = f2b(v[0]); r.y = f2b(v[1]); r.z = f2b(v[2]); r.w = f2b(v[3]);
    *(ushort4*)(dst + i) = r;
}

// ---------------------------------------------------------------------------
// Projections + XCD-locality swizzle (round-10 proven: -3.5 us).
// z=0: Q = x@Wq.T (scaled), z=1: K = x@Wk.T  -> row-major bf16.
// z=2: VT = Wv@x.T directly -> VT[(b*8+h)*64+d][t], coalesced along t.
// ---------------------------------------------------------------------------
__global__ __launch_bounds__(256, 3) void proj_gemm(
        const unsigned short* __restrict__ X,
        const unsigned short* __restrict__ Wbase,
        const float* __restrict__ bias0, const float* __restrict__ bias1,
        const float* __restrict__ bias2,
        unsigned short* __restrict__ Obase, unsigned short* __restrict__ VTb,
        float scale0) {
    // XCD-locality decode: p -> (xcd, m, slot) -> logical (xb4, y, z)
    const int p = blockIdx.x + 4 * (blockIdx.y + 64 * blockIdx.z);  // 0..767
    const int xcd = p & 7, r = p >> 3;
    const int m = r & 3, slot = r >> 2;           // m: col-block, slot: 0..23
    const int G = xcd + 8 * slot;                 // 0..191
    const int z = G >> 6, y = G & 63;

    const float* bias = (z == 0) ? bias0 : (z == 1 ? bias1 : bias2);
    const float scale = (z == 0) ? scale0 : 1.0f;

    int rowBase, colBase;
    const unsigned short *Ap, *Bp;
    if (z == 2) {   // A = Wv (rows=d), B = x (rows=t)
        rowBase = m * 128;  colBase = y * 128;
        Ap = Wbase + 2 * (ND * ND);  Bp = X;
    } else {        // A = x (rows=t), B = Wq/Wk (rows=d)
        rowBase = y * 128;  colBase = m * 128;
        Ap = X;                      Bp = Wbase + (size_t)z * (ND * ND);
    }

    __shared__ alignas(16) unsigned short ldsA[128 * 64];   // 16 KB
    __shared__ alignas(16) unsigned short ldsW[128 * 64];   // 16 KB

    const int tid = threadIdx.x;
    const int lane = tid & 63, wave = tid >> 6;
    const int quad = lane >> 4, l15 = lane & 15;
    const int wm = wave >> 1, wn = wave & 1;

    const int rS = tid >> 3;                      // 0..31
    const int gc = (tid & 7) ^ (rS & 7);          // call-invariant
    const unsigned short* gA = Ap + (size_t)(rowBase + rS) * ND + gc * 8;
    const unsigned short* gW = Bp + (size_t)(colBase + rS) * ND + gc * 8;
    const int ldst = wave * 512;                  // + c*2048

    const int swz = l15 & 7;

    f32x4 acc[4][4];
#pragma unroll
    for (int i = 0; i < 4; i++)
#pragma unroll
        for (int j = 0; j < 4; j++) acc[i][j] = (f32x4)0.0f;

    for (int kt = 0; kt < ND / 64; ++kt) {
        __syncthreads();
#pragma unroll
        for (int c = 0; c < 4; ++c) {
            load_lds16(gA + (size_t)c * 32 * ND, ldsA + c * 2048 + ldst);
            load_lds16(gW + (size_t)c * 32 * ND, ldsW + c * 2048 + ldst);
        }
        gA += 64; gW += 64;
        __syncthreads();

        __builtin_amdgcn_s_setprio(1);
#pragma unroll
        for (int ks = 0; ks < 2; ++ks) {
            short8 af[4], bfm[4];
#pragma unroll
            for (int mt = 0; mt < 4; ++mt)
                af[mt] = *(const short8*)(ldsA + (wm * 64 + mt * 16 + l15) * 64
                                          + (((ks * 4 + quad) ^ swz) * 8));
#pragma unroll
            for (int nt = 0; nt < 4; ++nt)
                bfm[nt] = *(const short8*)(ldsW + (wn * 64 + nt * 16 + l15) * 64
                                           + (((ks * 4 + quad) ^ swz) * 8));
#pragma unroll
            for (int mt = 0; mt < 4; ++mt)
#pragma unroll
                for (int nt = 0; nt < 4; ++nt)
                    acc[mt][nt] = __builtin_amdgcn_mfma_f32_16x16x32_bf16(
                        af[mt], bfm[nt], acc[mt][nt], 0, 0, 0);
        }
        __builtin_amdgcn_s_setprio(0);
    }

    if (z == 2) {
        const int bz = colBase >> 11;
        const int t0 = colBase & 2047;
        unsigned short* VTo = VTb + ((size_t)(bz * 512 + rowBase)) * NT + t0;
#pragma unroll
        for (int mt = 0; mt < 4; mt++)
#pragma unroll
            for (int reg = 0; reg < 4; reg++) {
                int mm = wm * 64 + mt * 16 + quad * 4 + reg;
                float bm = bias[rowBase + mm];
                unsigned short* dst = VTo + (size_t)mm * NT + wn * 64 + l15;
#pragma unroll
                for (int nt = 0; nt < 4; nt++)
                    dst[nt * 16] = f2b(acc[mt][nt][reg] + bm);
            }
    } else {
        float biasr[4];
#pragma unroll
        for (int nt = 0; nt < 4; nt++)
            biasr[nt] = bias[colBase + wn * 64 + nt * 16 + l15];
        unsigned short* Oz = Obase + (size_t)z * ((size_t)NM * ND);
#pragma unroll
        for (int mt = 0; mt < 4; mt++) {
            int row = rowBase + wm * 64 + mt * 16 + quad * 4;
#pragma unroll
            for (int reg = 0; reg < 4; reg++) {
                unsigned short* dst = Oz + (size_t)(row + reg) * ND + colBase + wn * 64 + l15;
#pragma unroll
                for (int nt = 0; nt < 4; nt++)
                    dst[nt * 16] = f2b((acc[mt][nt][reg] + biasr[nt]) * scale);
            }
        }
    }
}

// ---------------------------------------------------------------------------
// Output projection + XCD-locality swizzle (round-10 proven).
// ---------------------------------------------------------------------------
__global__ __launch_bounds__(256, 4) void out_gemm(
        const unsigned short* __restrict__ A, const unsigned short* __restrict__ W,
        const float* __restrict__ bias, float* __restrict__ OF) {
    __shared__ alignas(16) unsigned short ldsA[64 * 64];    // 8 KB
    __shared__ alignas(16) unsigned short ldsW[128 * 64];   // 16 KB

    // XCD-locality decode: 512 blocks -> (xcd, m, slot); G = row-group
    const int p = blockIdx.x + 4 * blockIdx.y;    // 0..511
    const int xcd = p & 7, r = p >> 3;
    const int m = r & 3, slot = r >> 2;           // slot 0..15
    const int G = xcd + 8 * slot;                 // 0..127
    const int rowBase = G * 64;
    const int colBase = m * 128;

    const int tid = threadIdx.x;
    const int lane = tid & 63, wave = tid >> 6;
    const int quad = lane >> 4, l15 = lane & 15;
    const int wm = wave >> 1, wn = wave & 1;

    const int rS = tid >> 3;
    const int gc = (tid & 7) ^ (rS & 7);
    const unsigned short* gA = A + (size_t)(rowBase + rS) * ND + gc * 8;
    const unsigned short* gW = W + (size_t)(colBase + rS) * ND + gc * 8;
    const int ldst = wave * 512;
    const int swz = l15 & 7;

    f32x4 acc[2][4];
#pragma unroll
    for (int mt = 0; mt < 2; mt++)
#pragma unroll
        for (int nt = 0; nt < 4; nt++) acc[mt][nt] = (f32x4)0.0f;

    for (int kt = 0; kt < ND / 64; ++kt) {
        __syncthreads();
#pragma unroll
        for (int c = 0; c < 2; ++c)
            load_lds16(gA + (size_t)c * 32 * ND, ldsA + c * 2048 + ldst);
#pragma unroll
        for (int c = 0; c < 4; ++c)
            load_lds16(gW + (size_t)c * 32 * ND, ldsW + c * 2048 + ldst);
        gA += 64; gW += 64;
        __syncthreads();

        __builtin_amdgcn_s_setprio(1);
#pragma unroll
        for (int ks = 0; ks < 2; ++ks) {
            short8 af[2], bfm[4];
#pragma unroll
            for (int mt = 0; mt < 2; ++mt)
                af[mt] = *(const short8*)(ldsA + (wm * 32 + mt * 16 + l15) * 64
                                          + (((ks * 4 + quad) ^ swz) * 8));
#pragma unroll
            for (int nt = 0; nt < 4; ++nt)
                bfm[nt] = *(const short8*)(ldsW + (wn * 64 + nt * 16 + l15) * 64
                                           + (((ks * 4 + quad) ^ swz) * 8));
#pragma unroll
            for (int mt = 0; mt < 2; ++mt)
#pragma unroll
                for (int nt = 0; nt < 4; ++nt)
                    acc[mt][nt] = __builtin_amdgcn_mfma_f32_16x16x32_bf16(
                        af[mt], bfm[nt], acc[mt][nt], 0, 0, 0);
        }
        __builtin_amdgcn_s_setprio(0);
    }

    float biasr[4];
#pragma unroll
    for (int nt = 0; nt < 4; nt++)
        biasr[nt] = bias[colBase + wn * 64 + nt * 16 + l15];

#pragma unroll
    for (int mt = 0; mt < 2; mt++)
#pragma unroll
        for (int reg = 0; reg < 4; reg++) {
            int row = rowBase + wm * 32 + mt * 16 + quad * 4 + reg;
            float* dst = OF + (size_t)row * ND + colBase + wn * 64 + l15;
#pragma unroll
            for (int nt = 0; nt < 4; nt++)
                dst[nt * 16] = acc[mt][nt][reg] + biasr[nt];
        }
}

// ---------------------------------------------------------------------------
// Flash attention v19 = round-10 attn + wave-parity pp-order stagger.
// Theory: per-round cycles (6300) ~2x the max-pipe floor (~3100) because the
// barrier phases all 16 waves into simultaneous LDS-read bursts then
// simultaneous VALU/MFMA phases (convoy). Odd waves now process their two
// 32-key blocks in reverse order (pp = ppi ^ (wave&1)) — accumulation is
// order-invariant, but odd/even waves touch disjoint LDS regions and offset
// their pipe phases by ~half a block, smoothing the burst.
// ---------------------------------------------------------------------------
__global__ __launch_bounds__(512, 4) void attn_kernel(
        const unsigned short* __restrict__ Qb, const unsigned short* __restrict__ Kb,
        const unsigned short* __restrict__ VTb, unsigned short* __restrict__ Cb) {
    // XCD-aware remap (bijective, 512 % 8 == 0)
    const int L = blockIdx.x + 16 * (blockIdx.y + 8 * blockIdx.z);   // 0..511
    const int s = L >> 3;                                            // 0..63
    const int qt = s & 15;
    const int g = (L & 7) + 8 * (s >> 4);                            // 0..31
    const int h = g & 7, b = g >> 3;

    __shared__ alignas(16) unsigned short Ks[2 * 8192];   // 2 x 16 KB [128][64]
    __shared__ alignas(16) unsigned short Vt[2 * 8192];   // 2 x 16 KB [64][128]

    const int tid = threadIdx.x, lane = tid & 63, wave = tid >> 6;   // 0..7
    const int wq = wave & 3, half = wave >> 2;
    const int wpar = wave & 1;                     // parity for pp stagger
    const int quad = lane >> 4, l15 = lane & 15;
    const size_t headOff = (size_t)h * NDK;
    const size_t rowB = (size_t)b * NT;
    const unsigned short* VT = VTb + (size_t)(b * NH + h) * ((size_t)NDK * NT);

    // Q fragments: wave covers queries qt*128 + wq*32 + t*16 + l15
    short8 aq[2][2];
#pragma unroll
    for (int t = 0; t < 2; ++t)
#pragma unroll
        for (int ks = 0; ks < 2; ++ks)
            aq[t][ks] = *(const short8*)(Qb
                + (rowB + qt * 128 + wq * 32 + t * 16 + l15) * ND
                + headOff + ks * 32 + quad * 8);

    // K staging (512 thr, 2 calls): LDS row r = c*64 + (tid>>3); within each
    // 32-row block the source key is kappa-permuted (PV K=32 fragment order).
    const int rK = tid >> 3;                      // 0..63
    const int rb = rK & 31;
    const int kap = (rb < 16) ? ((rb >> 2) * 8 + (rb & 3))
                              : (((rb - 16) >> 2) * 8 + 4 + ((rb - 16) & 3));
    const int gK8 = (tid & 7) ^ (rK & 7);         // storage XOR keyed on LDS row
    const unsigned short* gK = Kb + (rowB + (rK & 32) + kap) * ND + headOff + gK8 * 8;
    // V staging: linear d rows r = c*32 + (tid>>4), chunk XOR on source
    const int rV = tid >> 4;                      // 0..31
    const int gV8 = (tid & 15) ^ (rV & 7);
    const unsigned short* gV = VT + (size_t)rV * NT + gV8 * 8;
    const int ldst = wave * 512;                  // shorts; HW adds lane*16B

    // hoisted LDS read offsets (shorts)
    const int swz = l15 & 7;
    const int ko0 = l15 * 64 + ((quad ^ swz) * 8);          // dk 0..31 chunk
    const int ko1 = l15 * 64 + (((4 + quad) ^ swz) * 8);    // dk 32..63 chunk

    // ones bf16 fragment for MFMA row-sum
    const short8 ones = {0x3F80, 0x3F80, 0x3F80, 0x3F80,
                         0x3F80, 0x3F80, 0x3F80, 0x3F80};

    f32x4 o[2][4];
#pragma unroll
    for (int t = 0; t < 2; ++t)
#pragma unroll
        for (int nt = 0; nt < 4; ++nt) o[t][nt] = (f32x4)0.0f;
    f32x4 lsum[2] = {(f32x4)0.0f, (f32x4)0.0f};

    auto STAGE = [&](int bb, int r) {
        const unsigned short* k = gK + (size_t)r * 128 * ND;
        const unsigned short* v = gV + (size_t)r * 128;
        unsigned short* kd = Ks + bb * 8192 + ldst;
        unsigned short* vd = Vt + bb * 8192 + ldst;
#pragma unroll
        for (int c = 0; c < 2; ++c) {
            load_lds16(k + (size_t)c * 64 * ND, kd + c * 4096);
            load_lds16(v + (size_t)c * 32 * NT, vd + c * 4096);
        }
    };

    STAGE(0, 0);
    __syncthreads();                          // drain prologue loads (once)

    for (int kv = 0; kv < 16; ++kv) {
        const int buf = kv & 1;
        if (kv < 15) STAGE(buf ^ 1, kv + 1);  // prefetch overlaps compute below

        const unsigned short* KB = Ks + buf * 8192;
        const unsigned short* VB = Vt + buf * 8192;
        __builtin_amdgcn_s_setprio(1);
#pragma unroll
        for (int ppi = 0; ppi < 2; ++ppi) {   // parity-staggered block order
            const int pp = ppi ^ wpar;
            const int pb = half * 2 + pp;
            short8 kA0 = *(const short8*)(KB + pb * 2048 + ko0);
            short8 kA1 = *(const short8*)(KB + pb * 2048 + ko1);
            short8 kB0 = *(const short8*)(KB + pb * 2048 + 1024 + ko0);
            short8 kB1 = *(const short8*)(KB + pb * 2048 + 1024 + ko1);
            const int vo = l15 * 128 + (((pb * 4 + quad) ^ swz) * 8);
            short8 vf[4];
#pragma unroll
            for (int nt = 0; nt < 4; ++nt)
                vf[nt] = *(const short8*)(VB + vo + nt * 2048);

#pragma unroll
            for (int t = 0; t < 2; ++t) {
                f32x4 sa = (f32x4)0.0f, sb = (f32x4)0.0f;
                sa = __builtin_amdgcn_mfma_f32_16x16x32_bf16(kA0, aq[t][0], sa, 0, 0, 0);
                sa = __builtin_amdgcn_mfma_f32_16x16x32_bf16(kA1, aq[t][1], sa, 0, 0, 0);
                sb = __builtin_amdgcn_mfma_f32_16x16x32_bf16(kB0, aq[t][0], sb, 0, 0, 0);
                sb = __builtin_amdgcn_mfma_f32_16x16x32_bf16(kB1, aq[t][1], sb, 0, 0, 0);
                float pA0 = __builtin_amdgcn_exp2f(sa[0]), pA1 = __builtin_amdgcn_exp2f(sa[1]);
                float pA2 = __builtin_amdgcn_exp2f(sa[2]), pA3 = __builtin_amdgcn_exp2f(sa[3]);
                float pB0 = __builtin_amdgcn_exp2f(sb[0]), pB1 = __builtin_amdgcn_exp2f(sb[1]);
                float pB2 = __builtin_amdgcn_exp2f(sb[2]), pB3 = __builtin_amdgcn_exp2f(sb[3]);
                union { uint32_t w[4]; short8 v; } cv;
                cv.w[0] = __builtin_amdgcn_perm(__float_as_uint(pA1), __float_as_uint(pA0), 0x07060302u);
                cv.w[1] = __builtin_amdgcn_perm(__float_as_uint(pA3), __float_as_uint(pA2), 0x07060302u);
                cv.w[2] = __builtin_amdgcn_perm(__float_as_uint(pB1), __float_as_uint(pB0), 0x07060302u);
                cv.w[3] = __builtin_amdgcn_perm(__float_as_uint(pB3), __float_as_uint(pB2), 0x07060302u);
                lsum[t] = __builtin_amdgcn_mfma_f32_16x16x32_bf16(
                    cv.v, ones, lsum[t], 0, 0, 0);
#pragma unroll
                for (int nt = 0; nt < 4; ++nt)
                    o[t][nt] = __builtin_amdgcn_mfma_f32_16x16x32_bf16(
                        cv.v, vf[nt], o[t][nt], 0, 0, 0);
            }
        }
        __builtin_amdgcn_s_setprio(0);
        __syncthreads();   // forced vmcnt(0) drains prefetch AFTER compute
    }

    // ---- combine the two KV-halves through LDS scratch (once) ----
    // o: swizzled (t*4+nt)^(lane&7); lsum: f32x4 with (t^(lane&1)) swizzle
    f32x4* sc4  = (f32x4*)Ks;                 // 2048 f32x4 = 32 KB (all of Ks)
    f32x4* scl4 = (f32x4*)Vt;                 // 512 f32x4 = 8 KB of Vt
    const int lx = lane & 7;
    const int base = wq * 64 + lane;          // 0..255
    if (half) {
#pragma unroll
        for (int t = 0; t < 2; ++t) {
            scl4[base * 2 + (t ^ (lane & 1))] = lsum[t];
#pragma unroll
            for (int nt = 0; nt < 4; ++nt)
                sc4[base * 8 + ((t * 4 + nt) ^ lx)] = o[t][nt];
        }
    }
    __syncthreads();
    if (!half) {
#pragma unroll
        for (int t = 0; t < 2; ++t) {
            lsum[t] += scl4[base * 2 + (t ^ (lane & 1))];
#pragma unroll
            for (int nt = 0; nt < 4; ++nt)
                o[t][nt] += sc4[base * 8 + ((t * 4 + nt) ^ lx)];
#pragma unroll
            for (int reg = 0; reg < 4; ++reg) {
                float inv = 1.0f / lsum[t][reg];
                size_t row = rowB + qt * 128 + wq * 32 + t * 16 + quad * 4 + reg;
#pragma unroll
                for (int nt = 0; nt < 4; ++nt)
                    Cb[row * ND + headOff + nt * 16 + l15] = f2b(o[t][nt][reg] * inv);
            }
        }
    }
}

// ---------------------------------------------------------------------------
extern "C" void kernel_launch(void* const* d_in, const int* in_sizes, int n_in,
                              void* d_out, int out_size, void* d_ws, size_t ws_size,
                              hipStream_t stream) {
    (void)in_sizes; (void)n_in; (void)out_size; (void)ws_size;
    const float* x  = (const float*)d_in[0];
    const float* Wq = (const float*)d_in[1];
    const float* bq = (const float*)d_in[2];
    const float* Wk = (const float*)d_in[3];
    const float* bk = (const float*)d_in[4];
    const float* Wv = (const float*)d_in[5];
    const float* bv = (const float*)d_in[6];
    const float* Wo = (const float*)d_in[7];
    const float* bo = (const float*)d_in[8];
    float* out = (float*)d_out;

    unsigned short* ws  = (unsigned short*)d_ws;
    unsigned short* xb  = ws;                   // 4194304 elems
    unsigned short* wqb = xb + 4194304;         // 4 x 262144 (wq,wk,wv,wo)
    unsigned short* Qb  = wqb + 4 * 262144;     // Q,K,VT,C 4194304 each
    unsigned short* Kb  = Qb + 4194304;
    unsigned short* VTb = Kb + 4194304;
    unsigned short* Cb  = VTb + 4194304;
    unsigned short* wob = wqb + 3 * 262144;

    convert_all<<<5120, 256, 0, stream>>>(x, Wq, Wk, Wv, Wo, ws);

    // fold 1/sqrt(dk) * log2(e) into Q so softmax uses exp2
    const float qscale = 0.125f * 1.44269504f;
    proj_gemm<<<dim3(4, 64, 3), 256, 0, stream>>>(xb, wqb, bq, bk, bv, Qb, VTb, qscale);
    attn_kernel<<<dim3(16, 8, 4), 512, 0, stream>>>(Qb, Kb, VTb, Cb);
    out_gemm<<<dim3(4, 128), 256, 0, stream>>>(Cb, wob, bo, out);
}

// Round 12
// 144.670 us; speedup vs baseline: 1.0363x; 1.0363x over previous
//
#include <hip/hip_runtime.h>
#include <stdint.h>

#define NB 4
#define NT 2048
#define ND 512
#define NH 8
#define NDK 64
#define NM (NB*NT)   // 8192 rows

typedef __attribute__((ext_vector_type(8))) short short8;
typedef __attribute__((ext_vector_type(4))) float f32x4;

// round-to-nearest-even fp32 -> bf16
__device__ __forceinline__ unsigned short f2b(float f) {
    union { float f; uint32_t u; } v; v.f = f;
    return (unsigned short)((v.u + 0x7FFFu + ((v.u >> 16) & 1u)) >> 16);
}

__device__ __forceinline__ void load_lds16(const void* g, void* l) {
    void* gn = const_cast<void*>(g);
    __builtin_amdgcn_global_load_lds((__attribute__((address_space(1))) void*)gn,
                                     (__attribute__((address_space(3))) void*)l,
                                     16, 0, 0);
}

// ---------------------------------------------------------------------------
// fp32 -> bf16 conversion of x + Wq,Wk,Wv,Wo, packed into ws.
// ---------------------------------------------------------------------------
__global__ void convert_all(const float* __restrict__ x,  const float* __restrict__ wq,
                            const float* __restrict__ wk, const float* __restrict__ wv,
                            const float* __restrict__ wo, unsigned short* __restrict__ dst) {
    size_t i = ((size_t)blockIdx.x * 256 + threadIdx.x) * 4;
    const float* src; size_t off;
    if (i < 4194304) { src = x; off = i; }
    else {
        size_t j = i - 4194304;
        src = (j < 262144) ? wq : (j < 524288) ? wk : (j < 786432) ? wv : wo;
        off = j & 262143;
    }
    f32x4 v = *(const f32x4*)(src + off);
    ushort4 r;
    r.x = f2b(v[0]); r.y = f2b(v[1]); r.z = f2b(v[2]); r.w = f2b(v[3]);
    *(ushort4*)(dst + i) = r;
}

// ---------------------------------------------------------------------------
// Projections + XCD-locality swizzle (round-10 proven: -3.5 us).
// z=0: Q = x@Wq.T (scaled), z=1: K = x@Wk.T  -> row-major bf16.
// z=2: VT = Wv@x.T directly -> VT[(b*8+h)*64+d][t], coalesced along t.
// ---------------------------------------------------------------------------
__global__ __launch_bounds__(256, 3) void proj_gemm(
        const unsigned short* __restrict__ X,
        const unsigned short* __restrict__ Wbase,
        const float* __restrict__ bias0, const float* __restrict__ bias1,
        const float* __restrict__ bias2,
        unsigned short* __restrict__ Obase, unsigned short* __restrict__ VTb,
        float scale0) {
    // XCD-locality decode: p -> (xcd, m, slot) -> logical (xb4, y, z)
    const int p = blockIdx.x + 4 * (blockIdx.y + 64 * blockIdx.z);  // 0..767
    const int xcd = p & 7, r = p >> 3;
    const int m = r & 3, slot = r >> 2;           // m: col-block, slot: 0..23
    const int G = xcd + 8 * slot;                 // 0..191
    const int z = G >> 6, y = G & 63;

    const float* bias = (z == 0) ? bias0 : (z == 1 ? bias1 : bias2);
    const float scale = (z == 0) ? scale0 : 1.0f;

    int rowBase, colBase;
    const unsigned short *Ap, *Bp;
    if (z == 2) {   // A = Wv (rows=d), B = x (rows=t)
        rowBase = m * 128;  colBase = y * 128;
        Ap = Wbase + 2 * (ND * ND);  Bp = X;
    } else {        // A = x (rows=t), B = Wq/Wk (rows=d)
        rowBase = y * 128;  colBase = m * 128;
        Ap = X;                      Bp = Wbase + (size_t)z * (ND * ND);
    }

    __shared__ alignas(16) unsigned short ldsA[128 * 64];   // 16 KB
    __shared__ alignas(16) unsigned short ldsW[128 * 64];   // 16 KB

    const int tid = threadIdx.x;
    const int lane = tid & 63, wave = tid >> 6;
    const int quad = lane >> 4, l15 = lane & 15;
    const int wm = wave >> 1, wn = wave & 1;

    const int rS = tid >> 3;                      // 0..31
    const int gc = (tid & 7) ^ (rS & 7);          // call-invariant
    const unsigned short* gA = Ap + (size_t)(rowBase + rS) * ND + gc * 8;
    const unsigned short* gW = Bp + (size_t)(colBase + rS) * ND + gc * 8;
    const int ldst = wave * 512;                  // + c*2048

    const int swz = l15 & 7;

    f32x4 acc[4][4];
#pragma unroll
    for (int i = 0; i < 4; i++)
#pragma unroll
        for (int j = 0; j < 4; j++) acc[i][j] = (f32x4)0.0f;

    for (int kt = 0; kt < ND / 64; ++kt) {
        __syncthreads();
#pragma unroll
        for (int c = 0; c < 4; ++c) {
            load_lds16(gA + (size_t)c * 32 * ND, ldsA + c * 2048 + ldst);
            load_lds16(gW + (size_t)c * 32 * ND, ldsW + c * 2048 + ldst);
        }
        gA += 64; gW += 64;
        __syncthreads();

        __builtin_amdgcn_s_setprio(1);
#pragma unroll
        for (int ks = 0; ks < 2; ++ks) {
            short8 af[4], bfm[4];
#pragma unroll
            for (int mt = 0; mt < 4; ++mt)
                af[mt] = *(const short8*)(ldsA + (wm * 64 + mt * 16 + l15) * 64
                                          + (((ks * 4 + quad) ^ swz) * 8));
#pragma unroll
            for (int nt = 0; nt < 4; ++nt)
                bfm[nt] = *(const short8*)(ldsW + (wn * 64 + nt * 16 + l15) * 64
                                           + (((ks * 4 + quad) ^ swz) * 8));
#pragma unroll
            for (int mt = 0; mt < 4; ++mt)
#pragma unroll
                for (int nt = 0; nt < 4; ++nt)
                    acc[mt][nt] = __builtin_amdgcn_mfma_f32_16x16x32_bf16(
                        af[mt], bfm[nt], acc[mt][nt], 0, 0, 0);
        }
        __builtin_amdgcn_s_setprio(0);
    }

    if (z == 2) {
        const int bz = colBase >> 11;
        const int t0 = colBase & 2047;
        unsigned short* VTo = VTb + ((size_t)(bz * 512 + rowBase)) * NT + t0;
#pragma unroll
        for (int mt = 0; mt < 4; mt++)
#pragma unroll
            for (int reg = 0; reg < 4; reg++) {
                int mm = wm * 64 + mt * 16 + quad * 4 + reg;
                float bm = bias[rowBase + mm];
                unsigned short* dst = VTo + (size_t)mm * NT + wn * 64 + l15;
#pragma unroll
                for (int nt = 0; nt < 4; nt++)
                    dst[nt * 16] = f2b(acc[mt][nt][reg] + bm);
            }
    } else {
        float biasr[4];
#pragma unroll
        for (int nt = 0; nt < 4; nt++)
            biasr[nt] = bias[colBase + wn * 64 + nt * 16 + l15];
        unsigned short* Oz = Obase + (size_t)z * ((size_t)NM * ND);
#pragma unroll
        for (int mt = 0; mt < 4; mt++) {
            int row = rowBase + wm * 64 + mt * 16 + quad * 4;
#pragma unroll
            for (int reg = 0; reg < 4; reg++) {
                unsigned short* dst = Oz + (size_t)(row + reg) * ND + colBase + wn * 64 + l15;
#pragma unroll
                for (int nt = 0; nt < 4; nt++)
                    dst[nt * 16] = f2b((acc[mt][nt][reg] + biasr[nt]) * scale);
            }
        }
    }
}

// ---------------------------------------------------------------------------
// Output projection + XCD-locality swizzle (round-10 proven).
// ---------------------------------------------------------------------------
__global__ __launch_bounds__(256, 4) void out_gemm(
        const unsigned short* __restrict__ A, const unsigned short* __restrict__ W,
        const float* __restrict__ bias, float* __restrict__ OF) {
    __shared__ alignas(16) unsigned short ldsA[64 * 64];    // 8 KB
    __shared__ alignas(16) unsigned short ldsW[128 * 64];   // 16 KB

    // XCD-locality decode: 512 blocks -> (xcd, m, slot); G = row-group
    const int p = blockIdx.x + 4 * blockIdx.y;    // 0..511
    const int xcd = p & 7, r = p >> 3;
    const int m = r & 3, slot = r >> 2;           // slot 0..15
    const int G = xcd + 8 * slot;                 // 0..127
    const int rowBase = G * 64;
    const int colBase = m * 128;

    const int tid = threadIdx.x;
    const int lane = tid & 63, wave = tid >> 6;
    const int quad = lane >> 4, l15 = lane & 15;
    const int wm = wave >> 1, wn = wave & 1;

    const int rS = tid >> 3;
    const int gc = (tid & 7) ^ (rS & 7);
    const unsigned short* gA = A + (size_t)(rowBase + rS) * ND + gc * 8;
    const unsigned short* gW = W + (size_t)(colBase + rS) * ND + gc * 8;
    const int ldst = wave * 512;
    const int swz = l15 & 7;

    f32x4 acc[2][4];
#pragma unroll
    for (int mt = 0; mt < 2; mt++)
#pragma unroll
        for (int nt = 0; nt < 4; nt++) acc[mt][nt] = (f32x4)0.0f;

    for (int kt = 0; kt < ND / 64; ++kt) {
        __syncthreads();
#pragma unroll
        for (int c = 0; c < 2; ++c)
            load_lds16(gA + (size_t)c * 32 * ND, ldsA + c * 2048 + ldst);
#pragma unroll
        for (int c = 0; c < 4; ++c)
            load_lds16(gW + (size_t)c * 32 * ND, ldsW + c * 2048 + ldst);
        gA += 64; gW += 64;
        __syncthreads();

        __builtin_amdgcn_s_setprio(1);
#pragma unroll
        for (int ks = 0; ks < 2; ++ks) {
            short8 af[2], bfm[4];
#pragma unroll
            for (int mt = 0; mt < 2; ++mt)
                af[mt] = *(const short8*)(ldsA + (wm * 32 + mt * 16 + l15) * 64
                                          + (((ks * 4 + quad) ^ swz) * 8));
#pragma unroll
            for (int nt = 0; nt < 4; ++nt)
                bfm[nt] = *(const short8*)(ldsW + (wn * 64 + nt * 16 + l15) * 64
                                           + (((ks * 4 + quad) ^ swz) * 8));
#pragma unroll
            for (int mt = 0; mt < 2; ++mt)
#pragma unroll
                for (int nt = 0; nt < 4; ++nt)
                    acc[mt][nt] = __builtin_amdgcn_mfma_f32_16x16x32_bf16(
                        af[mt], bfm[nt], acc[mt][nt], 0, 0, 0);
        }
        __builtin_amdgcn_s_setprio(0);
    }

    float biasr[4];
#pragma unroll
    for (int nt = 0; nt < 4; nt++)
        biasr[nt] = bias[colBase + wn * 64 + nt * 16 + l15];

#pragma unroll
    for (int mt = 0; mt < 2; mt++)
#pragma unroll
        for (int reg = 0; reg < 4; reg++) {
            int row = rowBase + wm * 32 + mt * 16 + quad * 4 + reg;
            float* dst = OF + (size_t)row * ND + colBase + wn * 64 + l15;
#pragma unroll
            for (int nt = 0; nt < 4; nt++)
                dst[nt * 16] = acc[mt][nt][reg] + biasr[nt];
        }
}

// ---------------------------------------------------------------------------
// Flash attention v17 (round-10 best, byte-identical): v15 structure
// (32 q/wave, 2 blk/CU, half-split, setprio, swizzled combine) + MFMA-ones
// row-sum epilogue. pp-order stagger REVERTED (round-11: +3.5 us — runtime
// pb broke compile-time ds_read offset folding; keep LDS addressing
// compile-time-constant).
// ---------------------------------------------------------------------------
__global__ __launch_bounds__(512, 4) void attn_kernel(
        const unsigned short* __restrict__ Qb, const unsigned short* __restrict__ Kb,
        const unsigned short* __restrict__ VTb, unsigned short* __restrict__ Cb) {
    // XCD-aware remap (bijective, 512 % 8 == 0)
    const int L = blockIdx.x + 16 * (blockIdx.y + 8 * blockIdx.z);   // 0..511
    const int s = L >> 3;                                            // 0..63
    const int qt = s & 15;
    const int g = (L & 7) + 8 * (s >> 4);                            // 0..31
    const int h = g & 7, b = g >> 3;

    __shared__ alignas(16) unsigned short Ks[2 * 8192];   // 2 x 16 KB [128][64]
    __shared__ alignas(16) unsigned short Vt[2 * 8192];   // 2 x 16 KB [64][128]

    const int tid = threadIdx.x, lane = tid & 63, wave = tid >> 6;   // 0..7
    const int wq = wave & 3, half = wave >> 2;
    const int quad = lane >> 4, l15 = lane & 15;
    const size_t headOff = (size_t)h * NDK;
    const size_t rowB = (size_t)b * NT;
    const unsigned short* VT = VTb + (size_t)(b * NH + h) * ((size_t)NDK * NT);

    // Q fragments: wave covers queries qt*128 + wq*32 + t*16 + l15
    short8 aq[2][2];
#pragma unroll
    for (int t = 0; t < 2; ++t)
#pragma unroll
        for (int ks = 0; ks < 2; ++ks)
            aq[t][ks] = *(const short8*)(Qb
                + (rowB + qt * 128 + wq * 32 + t * 16 + l15) * ND
                + headOff + ks * 32 + quad * 8);

    // K staging (512 thr, 2 calls): LDS row r = c*64 + (tid>>3); within each
    // 32-row block the source key is kappa-permuted (PV K=32 fragment order).
    const int rK = tid >> 3;                      // 0..63
    const int rb = rK & 31;
    const int kap = (rb < 16) ? ((rb >> 2) * 8 + (rb & 3))
                              : (((rb - 16) >> 2) * 8 + 4 + ((rb - 16) & 3));
    const int gK8 = (tid & 7) ^ (rK & 7);         // storage XOR keyed on LDS row
    const unsigned short* gK = Kb + (rowB + (rK & 32) + kap) * ND + headOff + gK8 * 8;
    // V staging: linear d rows r = c*32 + (tid>>4), chunk XOR on source
    const int rV = tid >> 4;                      // 0..31
    const int gV8 = (tid & 15) ^ (rV & 7);
    const unsigned short* gV = VT + (size_t)rV * NT + gV8 * 8;
    const int ldst = wave * 512;                  // shorts; HW adds lane*16B

    // hoisted LDS read offsets (shorts)
    const int swz = l15 & 7;
    const int ko0 = l15 * 64 + ((quad ^ swz) * 8);          // dk 0..31 chunk
    const int ko1 = l15 * 64 + (((4 + quad) ^ swz) * 8);    // dk 32..63 chunk

    // ones bf16 fragment for MFMA row-sum (B-operand; D = row-sums of A
    // broadcast over all cols, landing at (quad*4+reg) like o's layout)
    const short8 ones = {0x3F80, 0x3F80, 0x3F80, 0x3F80,
                         0x3F80, 0x3F80, 0x3F80, 0x3F80};

    f32x4 o[2][4];
#pragma unroll
    for (int t = 0; t < 2; ++t)
#pragma unroll
        for (int nt = 0; nt < 4; ++nt) o[t][nt] = (f32x4)0.0f;
    f32x4 lsum[2] = {(f32x4)0.0f, (f32x4)0.0f};

    auto STAGE = [&](int bb, int r) {
        const unsigned short* k = gK + (size_t)r * 128 * ND;
        const unsigned short* v = gV + (size_t)r * 128;
        unsigned short* kd = Ks + bb * 8192 + ldst;
        unsigned short* vd = Vt + bb * 8192 + ldst;
#pragma unroll
        for (int c = 0; c < 2; ++c) {
            load_lds16(k + (size_t)c * 64 * ND, kd + c * 4096);
            load_lds16(v + (size_t)c * 32 * NT, vd + c * 4096);
        }
    };

    STAGE(0, 0);
    __syncthreads();                          // drain prologue loads (once)

    for (int kv = 0; kv < 16; ++kv) {
        const int buf = kv & 1;
        if (kv < 15) STAGE(buf ^ 1, kv + 1);  // prefetch overlaps compute below

        const unsigned short* KB = Ks + buf * 8192;
        const unsigned short* VB = Vt + buf * 8192;
        __builtin_amdgcn_s_setprio(1);
#pragma unroll
        for (int pp = 0; pp < 2; ++pp) {      // this wave's half of the tile
            const int pb = half * 2 + pp;
            short8 kA0 = *(const short8*)(KB + pb * 2048 + ko0);
            short8 kA1 = *(const short8*)(KB + pb * 2048 + ko1);
            short8 kB0 = *(const short8*)(KB + pb * 2048 + 1024 + ko0);
            short8 kB1 = *(const short8*)(KB + pb * 2048 + 1024 + ko1);
            const int vo = l15 * 128 + (((pb * 4 + quad) ^ swz) * 8);
            short8 vf[4];
#pragma unroll
            for (int nt = 0; nt < 4; ++nt)
                vf[nt] = *(const short8*)(VB + vo + nt * 2048);

#pragma unroll
            for (int t = 0; t < 2; ++t) {
                f32x4 sa = (f32x4)0.0f, sb = (f32x4)0.0f;
                sa = __builtin_amdgcn_mfma_f32_16x16x32_bf16(kA0, aq[t][0], sa, 0, 0, 0);
                sa = __builtin_amdgcn_mfma_f32_16x16x32_bf16(kA1, aq[t][1], sa, 0, 0, 0);
                sb = __builtin_amdgcn_mfma_f32_16x16x32_bf16(kB0, aq[t][0], sb, 0, 0, 0);
                sb = __builtin_amdgcn_mfma_f32_16x16x32_bf16(kB1, aq[t][1], sb, 0, 0, 0);
                float pA0 = __builtin_amdgcn_exp2f(sa[0]), pA1 = __builtin_amdgcn_exp2f(sa[1]);
                float pA2 = __builtin_amdgcn_exp2f(sa[2]), pA3 = __builtin_amdgcn_exp2f(sa[3]);
                float pB0 = __builtin_amdgcn_exp2f(sb[0]), pB1 = __builtin_amdgcn_exp2f(sb[1]);
                float pB2 = __builtin_amdgcn_exp2f(sb[2]), pB3 = __builtin_amdgcn_exp2f(sb[3]);
                union { uint32_t w[4]; short8 v; } cv;
                cv.w[0] = __builtin_amdgcn_perm(__float_as_uint(pA1), __float_as_uint(pA0), 0x07060302u);
                cv.w[1] = __builtin_amdgcn_perm(__float_as_uint(pA3), __float_as_uint(pA2), 0x07060302u);
                cv.w[2] = __builtin_amdgcn_perm(__float_as_uint(pB1), __float_as_uint(pB0), 0x07060302u);
                cv.w[3] = __builtin_amdgcn_perm(__float_as_uint(pB3), __float_as_uint(pB2), 0x07060302u);
                lsum[t] = __builtin_amdgcn_mfma_f32_16x16x32_bf16(
                    cv.v, ones, lsum[t], 0, 0, 0);
#pragma unroll
                for (int nt = 0; nt < 4; ++nt)
                    o[t][nt] = __builtin_amdgcn_mfma_f32_16x16x32_bf16(
                        cv.v, vf[nt], o[t][nt], 0, 0, 0);
            }
        }
        __builtin_amdgcn_s_setprio(0);
        __syncthreads();   // forced vmcnt(0) drains prefetch AFTER compute
    }

    // ---- combine the two KV-halves through LDS scratch (once) ----
    // o: swizzled (t*4+nt)^(lane&7); lsum: f32x4 with (t^(lane&1)) swizzle
    f32x4* sc4  = (f32x4*)Ks;                 // 2048 f32x4 = 32 KB (all of Ks)
    f32x4* scl4 = (f32x4*)Vt;                 // 512 f32x4 = 8 KB of Vt
    const int lx = lane & 7;
    const int base = wq * 64 + lane;          // 0..255
    if (half) {
#pragma unroll
        for (int t = 0; t < 2; ++t) {
            scl4[base * 2 + (t ^ (lane & 1))] = lsum[t];
#pragma unroll
            for (int nt = 0; nt < 4; ++nt)
                sc4[base * 8 + ((t * 4 + nt) ^ lx)] = o[t][nt];
        }
    }
    __syncthreads();
    if (!half) {
#pragma unroll
        for (int t = 0; t < 2; ++t) {
            lsum[t] += scl4[base * 2 + (t ^ (lane & 1))];
#pragma unroll
            for (int nt = 0; nt < 4; ++nt)
                o[t][nt] += sc4[base * 8 + ((t * 4 + nt) ^ lx)];
#pragma unroll
            for (int reg = 0; reg < 4; ++reg) {
                float inv = 1.0f / lsum[t][reg];
                size_t row = rowB + qt * 128 + wq * 32 + t * 16 + quad * 4 + reg;
#pragma unroll
                for (int nt = 0; nt < 4; ++nt)
                    Cb[row * ND + headOff + nt * 16 + l15] = f2b(o[t][nt][reg] * inv);
            }
        }
    }
}

// ---------------------------------------------------------------------------
extern "C" void kernel_launch(void* const* d_in, const int* in_sizes, int n_in,
                              void* d_out, int out_size, void* d_ws, size_t ws_size,
                              hipStream_t stream) {
    (void)in_sizes; (void)n_in; (void)out_size; (void)ws_size;
    const float* x  = (const float*)d_in[0];
    const float* Wq = (const float*)d_in[1];
    const float* bq = (const float*)d_in[2];
    const float* Wk = (const float*)d_in[3];
    const float* bk = (const float*)d_in[4];
    const float* Wv = (const float*)d_in[5];
    const float* bv = (const float*)d_in[6];
    const float* Wo = (const float*)d_in[7];
    const float* bo = (const float*)d_in[8];
    float* out = (float*)d_out;

    unsigned short* ws  = (unsigned short*)d_ws;
    unsigned short* xb  = ws;                   // 4194304 elems
    unsigned short* wqb = xb + 4194304;         // 4 x 262144 (wq,wk,wv,wo)
    unsigned short* Qb  = wqb + 4 * 262144;     // Q,K,VT,C 4194304 each
    unsigned short* Kb  = Qb + 4194304;
    unsigned short* VTb = Kb + 4194304;
    unsigned short* Cb  = VTb + 4194304;
    unsigned short* wob = wqb + 3 * 262144;

    convert_all<<<5120, 256, 0, stream>>>(x, Wq, Wk, Wv, Wo, ws);

    // fold 1/sqrt(dk) * log2(e) into Q so softmax uses exp2
    const float qscale = 0.125f * 1.44269504f;
    proj_gemm<<<dim3(4, 64, 3), 256, 0, stream>>>(xb, wqb, bq, bk, bv, Qb, VTb, qscale);
    attn_kernel<<<dim3(16, 8, 4), 512, 0, stream>>>(Qb, Kb, VTb, Cb);
    out_gemm<<<dim3(4, 128), 256, 0, stream>>>(Cb, wob, bo, out);
}